// Round 1
// baseline (2512.428 us; speedup 1.0000x reference)
//
#include <hip/hip_runtime.h>

// MaskedAtten: 8-layer transformer encoder fwd on MI355X (gfx950).
// B=8, T=255 -> L=256, D=1024, H=16, DH=64, NL=8, DFF=4096.
// Outputs: h[:,0] (8x1024 f32) then all_att (8,8,16,256,256 f32), concat flat.

using u16 = unsigned short;
typedef __attribute__((ext_vector_type(8))) __bf16 bf16x8;
typedef __attribute__((ext_vector_type(4))) float f32x4;
typedef __attribute__((ext_vector_type(8))) unsigned short ushort8;

__device__ __forceinline__ u16 f2b(float f) {
  unsigned u = __builtin_bit_cast(unsigned, f);
  return (u16)((u + 0x7FFFu + ((u >> 16) & 1u)) >> 16);  // RNE f32->bf16
}

__device__ __forceinline__ bf16x8 ldfrag(const u16* p) {
  return *reinterpret_cast<const bf16x8*>(p);
}

__device__ __forceinline__ f32x4 mfma16(bf16x8 a, bf16x8 b, f32x4 c) {
  return __builtin_amdgcn_mfma_f32_16x16x32_bf16(a, b, c, 0, 0, 0);
}

// async global->LDS, 16B per lane. LDS dest is wave-uniform base + lane*16.
__device__ __forceinline__ void gload16(const void* g, void* l) {
  __builtin_amdgcn_global_load_lds(
      (const __attribute__((address_space(1))) unsigned int*)g,
      (__attribute__((address_space(3))) unsigned int*)l, 16, 0, 0);
}

// ---------------- embed: h[b,l,d] = (l==0 ? sum_emb : x[b,l-1]) + mod_emb[l]
__global__ __launch_bounds__(256) void embed_k(
    const float* __restrict__ x, const float* __restrict__ sum_emb,
    const float* __restrict__ mod_emb, float* __restrict__ h) {
  int idx = blockIdx.x * 256 + threadIdx.x;  // 8*256*1024 total
  int d = idx & 1023;
  int l = (idx >> 10) & 255;
  int b = idx >> 18;
  float v = (l == 0) ? sum_emb[d] : x[(size_t)(b * 255 + l - 1) * 1024 + d];
  h[idx] = v + mod_emb[l * 1024 + d];
}

// ---------------- weight transpose + cast: in f32 [R][C] -> out bf16 [C][R]
__global__ __launch_bounds__(256) void transpose_w(
    const float* __restrict__ in, u16* __restrict__ out, int R, int C) {
  __shared__ float tile[32][33];
  const int t = threadIdx.x;
  const int r0 = blockIdx.y * 32, c0 = blockIdx.x * 32;
  const int tr = t >> 5, tc = t & 31;
#pragma unroll
  for (int i = 0; i < 4; ++i)
    tile[tr + i * 8][tc] = in[(size_t)(r0 + tr + i * 8) * C + c0 + tc];
  __syncthreads();
#pragma unroll
  for (int i = 0; i < 4; ++i) {
    int cc = tr + i * 8, rr = tc;
    out[(size_t)(c0 + cc) * R + r0 + rr] = f2b(tile[rr][cc]);
  }
}

// ---------------- LayerNorm row (1024) -> bf16 out, affine w,b
__global__ __launch_bounds__(256) void ln_bf16(
    const float* __restrict__ x, const float* __restrict__ w,
    const float* __restrict__ bb, u16* __restrict__ out) {
  const int r = blockIdx.x, t = threadIdx.x;
  const float* xr = x + (size_t)r * 1024;
  float v[4], s1 = 0.f, s2 = 0.f;
#pragma unroll
  for (int i = 0; i < 4; ++i) {
    v[i] = xr[t + i * 256];
    s1 += v[i];
    s2 += v[i] * v[i];
  }
#pragma unroll
  for (int o = 32; o > 0; o >>= 1) {
    s1 += __shfl_down(s1, o);
    s2 += __shfl_down(s2, o);
  }
  __shared__ float red[8];
  const int wv = t >> 6, l = t & 63;
  if (l == 0) { red[wv] = s1; red[4 + wv] = s2; }
  __syncthreads();
  s1 = red[0] + red[1] + red[2] + red[3];
  s2 = red[4] + red[5] + red[6] + red[7];
  float mean = s1 * (1.0f / 1024.0f);
  float var = s2 * (1.0f / 1024.0f) - mean * mean;
  float rstd = rsqrtf(var + 1e-5f);
#pragma unroll
  for (int i = 0; i < 4; ++i) {
    int c = t + i * 256;
    out[(size_t)r * 1024 + c] = f2b((v[i] - mean) * rstd * w[c] + bb[c]);
  }
}

// ---------------- final LN on the 8 summary rows -> f32 d_out[0:8192]
__global__ __launch_bounds__(256) void final_ln(
    const float* __restrict__ h, const float* __restrict__ w,
    const float* __restrict__ bb, float* __restrict__ out) {
  const int r = blockIdx.x, t = threadIdx.x;
  const float* xr = h + (size_t)r * 262144;  // row (b,0)
  float v[4], s1 = 0.f, s2 = 0.f;
#pragma unroll
  for (int i = 0; i < 4; ++i) {
    v[i] = xr[t + i * 256];
    s1 += v[i];
    s2 += v[i] * v[i];
  }
#pragma unroll
  for (int o = 32; o > 0; o >>= 1) {
    s1 += __shfl_down(s1, o);
    s2 += __shfl_down(s2, o);
  }
  __shared__ float red[8];
  const int wv = t >> 6, l = t & 63;
  if (l == 0) { red[wv] = s1; red[4 + wv] = s2; }
  __syncthreads();
  s1 = red[0] + red[1] + red[2] + red[3];
  s2 = red[4] + red[5] + red[6] + red[7];
  float mean = s1 * (1.0f / 1024.0f);
  float var = s2 * (1.0f / 1024.0f) - mean * mean;
  float rstd = rsqrtf(var + 1e-5f);
#pragma unroll
  for (int i = 0; i < 4; ++i) {
    int c = t + i * 256;
    out[r * 1024 + c] = (v[i] - mean) * rstd * w[c] + bb[c];
  }
}

// ---------------- GEMM: C[M,N] = A[M,K](bf16) @ BT[N,K](bf16)^T + bias, m97-style
// EPI 0: out bf16 ; EPI 1: Hres += (f32 residual) ; EPI 2: gelu -> bf16
template <int EPI>
__global__ __launch_bounds__(256) void gemm_bt(
    const u16* __restrict__ A, const u16* __restrict__ BT,
    const float* __restrict__ bias, float* __restrict__ Hres,
    u16* __restrict__ Obf, int M, int N, int K) {
  __shared__ u16 As[128 * 32];
  __shared__ u16 Bs[128 * 32];
  const int t = threadIdx.x;
  const int m0 = blockIdx.y * 128, n0 = blockIdx.x * 128;
  const int l = t & 63, w = t >> 6;
  const int wr = (w >> 1) * 64, wc = (w & 1) * 64;
  const int lr = l & 15, lh = l >> 4;

  const int srow = t >> 2;        // 0..63
  const int skc = (t & 3) * 8;    // 0,8,16,24
  const u16* Ag = A + (size_t)(m0 + srow) * K + skc;
  const u16* Bg = BT + (size_t)(n0 + srow) * K + skc;

  f32x4 acc[4][4] = {};
  const int nk = K / 32;
  for (int kt = 0; kt < nk; ++kt) {
    __syncthreads();  // previous tile fully consumed
    gload16(Ag, As + t * 8);
    gload16(Ag + (size_t)64 * K, As + 2048 + t * 8);
    gload16(Bg, Bs + t * 8);
    gload16(Bg + (size_t)64 * K, Bs + 2048 + t * 8);
    Ag += 32;
    Bg += 32;
    __syncthreads();  // staged (compiler drains vmcnt before barrier)
    bf16x8 af[4], bfr[4];
#pragma unroll
    for (int m = 0; m < 4; ++m) af[m] = ldfrag(As + (wr + m * 16 + lr) * 32 + lh * 8);
#pragma unroll
    for (int n = 0; n < 4; ++n) bfr[n] = ldfrag(Bs + (wc + n * 16 + lr) * 32 + lh * 8);
#pragma unroll
    for (int m = 0; m < 4; ++m)
#pragma unroll
      for (int n = 0; n < 4; ++n) acc[m][n] = mfma16(af[m], bfr[n], acc[m][n]);
  }
#pragma unroll
  for (int m = 0; m < 4; ++m) {
#pragma unroll
    for (int n = 0; n < 4; ++n) {
      const int col = n0 + wc + n * 16 + lr;
      const float bc = bias[col];
#pragma unroll
      for (int j = 0; j < 4; ++j) {
        const int row = m0 + wr + m * 16 + lh * 4 + j;
        float v = acc[m][n][j] + bc;
        if (EPI == 0) {
          Obf[(size_t)row * N + col] = f2b(v);
        } else if (EPI == 1) {
          size_t idx = (size_t)row * N + col;
          Hres[idx] = Hres[idx] + v;
        } else {
          float g = 0.5f * v *
                    (1.0f + tanhf(0.7978845608028654f * (v + 0.044715f * v * v * v)));
          Obf[(size_t)row * N + col] = f2b(g);
        }
      }
    }
  }
}

// ---------------- attention scores + softmax, per (b, head, 32-row q-tile)
// qkv bf16 [B*256, 3072]: q at col h*64, k at 1024+h*64, v at 2048+h*64.
// Writes att f32 (this layer's d_out slice) and att bf16 (ws, for PV).
__global__ __launch_bounds__(256) void attn_qk(
    const u16* __restrict__ qkv, const int* __restrict__ mask,
    float* __restrict__ att_out, u16* __restrict__ att_bf) {
  __shared__ u16 Qs[32 * 64];
  __shared__ u16 Ks[256 * 64];
  __shared__ float Sf[32 * 256];
  __shared__ float mbias[256];
  __shared__ float rmax[32], rsum[32];
  const int t = threadIdx.x;
  const int blk = blockIdx.x;
  const int qt = blk & 7, hh = (blk >> 3) & 15, b = blk >> 7;
  const int q0 = qt * 32;

  mbias[t] = (t == 0) ? 0.0f : ((mask[b * 255 + t - 1] == 1) ? 0.0f : -1e9f);

  // stage Q tile (32x64) with XOR chunk swizzle (row&7) to kill bank conflicts
  {
    int row = t >> 3, c = t & 7;
    int gcol = (c ^ (row & 7)) * 8;
    gload16(qkv + (size_t)(b * 256 + q0 + row) * 3072 + hh * 64 + gcol, Qs + t * 8);
  }
  // stage K (256x64), same swizzle
#pragma unroll
  for (int s = 0; s < 8; ++s) {
    int row = s * 32 + (t >> 3), c = t & 7;
    int gcol = (c ^ (row & 7)) * 8;
    gload16(qkv + (size_t)(b * 256 + row) * 3072 + 1024 + hh * 64 + gcol,
            Ks + s * 2048 + t * 8);
  }
  __syncthreads();

  const int l = t & 63, w = t >> 6;
  const int lr = l & 15, lh = l >> 4;
  const int c0 = w * 64;
  f32x4 acc[2][4] = {};
#pragma unroll
  for (int ks = 0; ks < 2; ++ks) {
    bf16x8 af[2], bfr[4];
#pragma unroll
    for (int m = 0; m < 2; ++m) {
      int row = m * 16 + lr;
      int chunk = (ks * 4 + lh) ^ (row & 7);
      af[m] = ldfrag(Qs + row * 64 + chunk * 8);
    }
#pragma unroll
    for (int n = 0; n < 4; ++n) {
      int row = c0 + n * 16 + lr;
      int chunk = (ks * 4 + lh) ^ (row & 7);
      bfr[n] = ldfrag(Ks + row * 64 + chunk * 8);
    }
#pragma unroll
    for (int m = 0; m < 2; ++m)
#pragma unroll
      for (int n = 0; n < 4; ++n) acc[m][n] = mfma16(af[m], bfr[n], acc[m][n]);
  }
#pragma unroll
  for (int m = 0; m < 2; ++m)
#pragma unroll
    for (int n = 0; n < 4; ++n) {
      const int col = c0 + n * 16 + lr;
      const float mb = mbias[col];
#pragma unroll
      for (int j = 0; j < 4; ++j) {
        int row = m * 16 + lh * 4 + j;
        Sf[row * 256 + col] = acc[m][n][j] * 0.125f + mb;
      }
    }
  __syncthreads();

  {  // row softmax stats: 8 threads per row; rotated column order vs bank aliasing
    const int row = t >> 3, tg = t & 7;
    float mx = -1e30f;
#pragma unroll 8
    for (int k = 0; k < 32; ++k) {
      int c = tg * 32 + ((k + row * 4 + tg) & 31);
      mx = fmaxf(mx, Sf[row * 256 + c]);
    }
    mx = fmaxf(mx, __shfl_xor(mx, 1));
    mx = fmaxf(mx, __shfl_xor(mx, 2));
    mx = fmaxf(mx, __shfl_xor(mx, 4));
    float sm = 0.f;
#pragma unroll 8
    for (int k = 0; k < 32; ++k) {
      int c = tg * 32 + ((k + row * 4 + tg) & 31);
      sm += expf(Sf[row * 256 + c] - mx);
    }
    sm += __shfl_xor(sm, 1);
    sm += __shfl_xor(sm, 2);
    sm += __shfl_xor(sm, 4);
    if (tg == 0) {
      rmax[row] = mx;
      rsum[row] = 1.0f / sm;
    }
  }
  __syncthreads();

  const size_t obase = ((size_t)b * 16 + hh) * 65536 + (size_t)q0 * 256;
#pragma unroll 4
  for (int i = 0; i < 32; ++i) {
    float p = expf(Sf[i * 256 + t] - rmax[i]) * rsum[i];
    att_out[obase + (size_t)i * 256 + t] = p;
    att_bf[obase + (size_t)i * 256 + t] = f2b(p);
  }
}

// ---------------- PV: Y[256,64] = P[256,256] @ V[256,64], per (b, head)
#define VS 264  // padded row stride (bf16 elems) for transposed V -> conflict-free b128
__global__ __launch_bounds__(256) void attn_pv(
    const u16* __restrict__ qkv, const u16* __restrict__ att_bf,
    u16* __restrict__ y) {
  __shared__ u16 Vt[64 * VS];
  const int t = threadIdx.x;
  const int b = blockIdx.x >> 4, hh = blockIdx.x & 15;
  const int l = t & 63, w = t >> 6;
  {  // stage V transposed: Vt[d][j] = V[j][d]
    const int j = w * 64 + l;
    const u16* vsrc = qkv + (size_t)(b * 256 + j) * 3072 + 2048 + hh * 64;
#pragma unroll
    for (int dd = 0; dd < 8; ++dd) {
      ushort8 v = *reinterpret_cast<const ushort8*>(vsrc + dd * 8);
#pragma unroll
      for (int e = 0; e < 8; ++e) Vt[(dd * 8 + e) * VS + j] = v[e];
    }
  }
  __syncthreads();
  const int lr = l & 15, lh = l >> 4;
  const int r0 = w * 64;
  const u16* Pg = att_bf + ((size_t)(b * 16 + hh)) * 65536;
  f32x4 acc[4][4] = {};
#pragma unroll
  for (int ks = 0; ks < 8; ++ks) {
    bf16x8 af[4], bfr[4];
#pragma unroll
    for (int m = 0; m < 4; ++m)
      af[m] = ldfrag(Pg + (size_t)(r0 + m * 16 + lr) * 256 + ks * 32 + lh * 8);
#pragma unroll
    for (int n = 0; n < 4; ++n)
      bfr[n] = ldfrag(Vt + (n * 16 + lr) * VS + ks * 32 + lh * 8);
#pragma unroll
    for (int m = 0; m < 4; ++m)
#pragma unroll
      for (int n = 0; n < 4; ++n) acc[m][n] = mfma16(af[m], bfr[n], acc[m][n]);
  }
#pragma unroll
  for (int m = 0; m < 4; ++m)
#pragma unroll
    for (int n = 0; n < 4; ++n)
#pragma unroll
      for (int j = 0; j < 4; ++j) {
        int row = r0 + m * 16 + lh * 4 + j;
        int col = n * 16 + lr;
        y[(size_t)(b * 256 + row) * 1024 + hh * 64 + col] = f2b(acc[m][n][j]);
      }
}

extern "C" void kernel_launch(void* const* d_in, const int* in_sizes, int n_in,
                              void* d_out, int out_size, void* d_ws, size_t ws_size,
                              hipStream_t stream) {
  (void)in_sizes; (void)n_in; (void)out_size; (void)ws_size;
  const float* x      = (const float*)d_in[0];
  const int* mask     = (const int*)d_in[1];
  // d_in[2] = is_train (0 in eval; input-drop loop is a no-op)
  const float* sum_emb = (const float*)d_in[3];
  const float* mod_emb = (const float*)d_in[4];
  const float* ln1_w  = (const float*)d_in[5];
  const float* ln1_b  = (const float*)d_in[6];
  const float* w_qkv  = (const float*)d_in[7];
  const float* b_qkv  = (const float*)d_in[8];
  const float* w_proj = (const float*)d_in[9];
  const float* b_proj = (const float*)d_in[10];
  const float* ln2_w  = (const float*)d_in[11];
  const float* ln2_b  = (const float*)d_in[12];
  const float* w_fc   = (const float*)d_in[13];
  const float* b_fc   = (const float*)d_in[14];
  const float* w_out  = (const float*)d_in[15];
  const float* b_out  = (const float*)d_in[16];
  const float* norm_w = (const float*)d_in[17];
  const float* norm_b = (const float*)d_in[18];

  // workspace carve (total 88,080,384 bytes)
  char* ws = (char*)d_ws;
  float* h    = (float*)(ws + 0);          // 8 MB   [2048,1024] f32 residual
  u16* wqkvT  = (u16*)(ws + 8388608);      // [3072][1024] bf16
  u16* wprojT = (u16*)(ws + 14680064);     // [1024][1024]
  u16* wfcT   = (u16*)(ws + 16777216);     // [4096][1024]
  u16* woutT  = (u16*)(ws + 25165824);     // [1024][4096]
  u16* a_bf   = (u16*)(ws + 33554432);     // [2048,1024] LN out
  u16* qkv_bf = (u16*)(ws + 37748736);     // [2048,3072]
  u16* att_bf = (u16*)(ws + 50331648);     // [128,256,256]
  u16* y_bf   = (u16*)(ws + 67108864);     // [2048,1024]
  u16* g_bf   = (u16*)(ws + 71303168);     // [2048,4096]
  float* att_f = (float*)d_out + 8192;

  embed_k<<<8192, 256, 0, stream>>>(x, sum_emb, mod_emb, h);

  for (int L = 0; L < 8; ++L) {
    const float* wqkv_l = w_qkv + (size_t)L * 1024 * 3072;
    const float* wproj_l = w_proj + (size_t)L * 1024 * 1024;
    const float* wfc_l = w_fc + (size_t)L * 1024 * 4096;
    const float* wout_l = w_out + (size_t)L * 4096 * 1024;

    transpose_w<<<dim3(96, 32), 256, 0, stream>>>(wqkv_l, wqkvT, 1024, 3072);
    transpose_w<<<dim3(32, 32), 256, 0, stream>>>(wproj_l, wprojT, 1024, 1024);
    transpose_w<<<dim3(128, 32), 256, 0, stream>>>(wfc_l, wfcT, 1024, 4096);
    transpose_w<<<dim3(32, 128), 256, 0, stream>>>(wout_l, woutT, 4096, 1024);

    ln_bf16<<<2048, 256, 0, stream>>>(h, ln1_w + L * 1024, ln1_b + L * 1024, a_bf);
    gemm_bt<0><<<dim3(24, 16), 256, 0, stream>>>(a_bf, wqkvT, b_qkv + L * 3072,
                                                 nullptr, qkv_bf, 2048, 3072, 1024);
    attn_qk<<<1024, 256, 0, stream>>>(qkv_bf, mask, att_f + (size_t)L * 8388608,
                                      att_bf);
    attn_pv<<<128, 256, 0, stream>>>(qkv_bf, att_bf, y_bf);
    gemm_bt<1><<<dim3(8, 16), 256, 0, stream>>>(y_bf, wprojT, b_proj + L * 1024, h,
                                                nullptr, 2048, 1024, 1024);
    ln_bf16<<<2048, 256, 0, stream>>>(h, ln2_w + L * 1024, ln2_b + L * 1024, a_bf);
    gemm_bt<2><<<dim3(32, 16), 256, 0, stream>>>(a_bf, wfcT, b_fc + L * 4096,
                                                 nullptr, g_bf, 2048, 4096, 1024);
    gemm_bt<1><<<dim3(8, 16), 256, 0, stream>>>(g_bf, woutT, b_out + L * 1024, h,
                                                nullptr, 2048, 1024, 4096);
  }

  final_ln<<<8, 256, 0, stream>>>(h, norm_w, norm_b, (float*)d_out);
}

// Round 3
// 2109.568 us; speedup vs baseline: 1.1910x; 1.1910x over previous
//
#include <hip/hip_runtime.h>

// MaskedAtten: 8-layer transformer encoder fwd on MI355X (gfx950).
// B=8, T=255 -> L=256, D=1024, H=16, DH=64, NL=8, DFF=4096.
// Outputs: h[:,0] (8x1024 f32) then all_att (8,8,16,256,256 f32), concat flat.

using u16 = unsigned short;
typedef __attribute__((ext_vector_type(8))) __bf16 bf16x8;
typedef __attribute__((ext_vector_type(4))) float f32x4;
typedef __attribute__((ext_vector_type(8))) unsigned short ushort8;

__device__ __forceinline__ u16 f2b(float f) {
  unsigned u = __builtin_bit_cast(unsigned, f);
  return (u16)((u + 0x7FFFu + ((u >> 16) & 1u)) >> 16);  // RNE f32->bf16
}

__device__ __forceinline__ bf16x8 ldfrag(const u16* p) {
  return *reinterpret_cast<const bf16x8*>(p);
}

__device__ __forceinline__ f32x4 mfma16(bf16x8 a, bf16x8 b, f32x4 c) {
  return __builtin_amdgcn_mfma_f32_16x16x32_bf16(a, b, c, 0, 0, 0);
}

// async global->LDS, 16B per lane. LDS dest is wave-uniform base + lane*16.
__device__ __forceinline__ void gload16(const void* g, void* l) {
  __builtin_amdgcn_global_load_lds(
      (const __attribute__((address_space(1))) unsigned int*)g,
      (__attribute__((address_space(3))) unsigned int*)l, 16, 0, 0);
}

// ---------------- embed: h[b,l,d] = (l==0 ? sum_emb : x[b,l-1]) + mod_emb[l]
__global__ __launch_bounds__(256) void embed_k(
    const float* __restrict__ x, const float* __restrict__ sum_emb,
    const float* __restrict__ mod_emb, float* __restrict__ h) {
  int idx = blockIdx.x * 256 + threadIdx.x;  // 8*256*1024 total
  int d = idx & 1023;
  int l = (idx >> 10) & 255;
  int b = idx >> 18;
  float v = (l == 0) ? sum_emb[d] : x[(size_t)(b * 255 + l - 1) * 1024 + d];
  h[idx] = v + mod_emb[l * 1024 + d];
}

// ---------------- weight transpose + cast: in f32 [R][C] -> out bf16 [C][R]
// blockIdx.z = layer (in/out advance by R*C elements per layer)
__global__ __launch_bounds__(256) void transpose_w(
    const float* __restrict__ in, u16* __restrict__ out, int R, int C) {
  __shared__ float tile[32][33];
  in += (size_t)blockIdx.z * R * C;
  out += (size_t)blockIdx.z * R * C;
  const int t = threadIdx.x;
  const int r0 = blockIdx.y * 32, c0 = blockIdx.x * 32;
  const int tr = t >> 5, tc = t & 31;
#pragma unroll
  for (int i = 0; i < 4; ++i)
    tile[tr + i * 8][tc] = in[(size_t)(r0 + tr + i * 8) * C + c0 + tc];
  __syncthreads();
#pragma unroll
  for (int i = 0; i < 4; ++i) {
    int cc = tr + i * 8, rr = tc;
    out[(size_t)(c0 + cc) * R + r0 + rr] = f2b(tile[rr][cc]);
  }
}

// ---------------- LayerNorm row (1024) -> bf16 out, affine w,b
__global__ __launch_bounds__(256) void ln_bf16(
    const float* __restrict__ x, const float* __restrict__ w,
    const float* __restrict__ bb, u16* __restrict__ out) {
  const int r = blockIdx.x, t = threadIdx.x;
  const float* xr = x + (size_t)r * 1024;
  float v[4], s1 = 0.f, s2 = 0.f;
#pragma unroll
  for (int i = 0; i < 4; ++i) {
    v[i] = xr[t + i * 256];
    s1 += v[i];
    s2 += v[i] * v[i];
  }
#pragma unroll
  for (int o = 32; o > 0; o >>= 1) {
    s1 += __shfl_down(s1, o);
    s2 += __shfl_down(s2, o);
  }
  __shared__ float red[8];
  const int wv = t >> 6, l = t & 63;
  if (l == 0) { red[wv] = s1; red[4 + wv] = s2; }
  __syncthreads();
  s1 = red[0] + red[1] + red[2] + red[3];
  s2 = red[4] + red[5] + red[6] + red[7];
  float mean = s1 * (1.0f / 1024.0f);
  float var = s2 * (1.0f / 1024.0f) - mean * mean;
  float rstd = rsqrtf(var + 1e-5f);
#pragma unroll
  for (int i = 0; i < 4; ++i) {
    int c = t + i * 256;
    out[(size_t)r * 1024 + c] = f2b((v[i] - mean) * rstd * w[c] + bb[c]);
  }
}

// ---------------- final LN on the 8 summary rows -> f32 d_out[0:8192]
__global__ __launch_bounds__(256) void final_ln(
    const float* __restrict__ h, const float* __restrict__ w,
    const float* __restrict__ bb, float* __restrict__ out) {
  const int r = blockIdx.x, t = threadIdx.x;
  const float* xr = h + (size_t)r * 262144;  // row (b,0)
  float v[4], s1 = 0.f, s2 = 0.f;
#pragma unroll
  for (int i = 0; i < 4; ++i) {
    v[i] = xr[t + i * 256];
    s1 += v[i];
    s2 += v[i] * v[i];
  }
#pragma unroll
  for (int o = 32; o > 0; o >>= 1) {
    s1 += __shfl_down(s1, o);
    s2 += __shfl_down(s2, o);
  }
  __shared__ float red[8];
  const int wv = t >> 6, l = t & 63;
  if (l == 0) { red[wv] = s1; red[4 + wv] = s2; }
  __syncthreads();
  s1 = red[0] + red[1] + red[2] + red[3];
  s2 = red[4] + red[5] + red[6] + red[7];
  float mean = s1 * (1.0f / 1024.0f);
  float var = s2 * (1.0f / 1024.0f) - mean * mean;
  float rstd = rsqrtf(var + 1e-5f);
#pragma unroll
  for (int i = 0; i < 4; ++i) {
    int c = t + i * 256;
    out[r * 1024 + c] = (v[i] - mean) * rstd * w[c] + bb[c];
  }
}

// ---------------- GEMM: C[M,N] = A[M,K](bf16) @ BT[N,K](bf16)^T + bias
// EPI 0: out bf16 ; EPI 1: Hres += (atomic if SPLIT>1) ; EPI 2: gelu -> bf16
// SPLIT: split-K factor, blockIdx.z = K-slice.
template <int EPI, int SPLIT>
__global__ __launch_bounds__(256) void gemm_bt(
    const u16* __restrict__ A, const u16* __restrict__ BT,
    const float* __restrict__ bias, float* __restrict__ Hres,
    u16* __restrict__ Obf, int M, int N, int K) {
  __shared__ u16 As[128 * 32];
  __shared__ u16 Bs[128 * 32];
  const int t = threadIdx.x;
  const int m0 = blockIdx.y * 128, n0 = blockIdx.x * 128;
  const int Kl = K / SPLIT;
  const int kz = (SPLIT > 1) ? blockIdx.z : 0;
  A += (size_t)kz * Kl;
  BT += (size_t)kz * Kl;
  const int l = t & 63, w = t >> 6;
  const int wr = (w >> 1) * 64, wc = (w & 1) * 64;
  const int lr = l & 15, lh = l >> 4;

  const int srow = t >> 2;        // 0..63
  const int skc = (t & 3) * 8;    // 0,8,16,24
  const u16* Ag = A + (size_t)(m0 + srow) * K + skc;
  const u16* Bg = BT + (size_t)(n0 + srow) * K + skc;

  f32x4 acc[4][4] = {};
  const int nk = Kl / 32;
  for (int kt = 0; kt < nk; ++kt) {
    __syncthreads();  // previous tile fully consumed
    gload16(Ag, As + t * 8);
    gload16(Ag + (size_t)64 * K, As + 2048 + t * 8);
    gload16(Bg, Bs + t * 8);
    gload16(Bg + (size_t)64 * K, Bs + 2048 + t * 8);
    Ag += 32;
    Bg += 32;
    __syncthreads();  // staged (compiler drains vmcnt before barrier)
    bf16x8 af[4], bfr[4];
#pragma unroll
    for (int m = 0; m < 4; ++m) af[m] = ldfrag(As + (wr + m * 16 + lr) * 32 + lh * 8);
#pragma unroll
    for (int n = 0; n < 4; ++n) bfr[n] = ldfrag(Bs + (wc + n * 16 + lr) * 32 + lh * 8);
#pragma unroll
    for (int m = 0; m < 4; ++m)
#pragma unroll
      for (int n = 0; n < 4; ++n) acc[m][n] = mfma16(af[m], bfr[n], acc[m][n]);
  }
#pragma unroll
  for (int m = 0; m < 4; ++m) {
#pragma unroll
    for (int n = 0; n < 4; ++n) {
      const int col = n0 + wc + n * 16 + lr;
      const float bc = (SPLIT == 1 || kz == 0) ? bias[col] : 0.0f;
#pragma unroll
      for (int j = 0; j < 4; ++j) {
        const int row = m0 + wr + m * 16 + lh * 4 + j;
        float v = acc[m][n][j] + bc;
        if (EPI == 0) {
          Obf[(size_t)row * N + col] = f2b(v);
        } else if (EPI == 1) {
          size_t idx = (size_t)row * N + col;
          if (SPLIT == 1) Hres[idx] = Hres[idx] + v;
          else atomicAdd(Hres + idx, v);
        } else {
          float g = 0.5f * v *
                    (1.0f + tanhf(0.7978845608028654f * (v + 0.044715f * v * v * v)));
          Obf[(size_t)row * N + col] = f2b(g);
        }
      }
    }
  }
}

// ---------------- fused attention per (b, head, 32-row q-tile):
// QK^T -> softmax -> write att f32 (d_out) -> PV -> write y bf16.
#define VS 264  // padded row stride for transposed V (conflict-free b128)
__device__ __forceinline__ int sfi(int row, int col) {
  return row * 256 + ((col & 7) | (((col >> 3) ^ (row & 7)) << 3));
}

__global__ __launch_bounds__(256) void attn_fused(
    const u16* __restrict__ qkv, const int* __restrict__ mask,
    float* __restrict__ att_out, u16* __restrict__ y) {
  __shared__ u16 Qs[32 * 64];
  __shared__ u16 KV[64 * VS];  // phase 1: K (256x64 = 16384 u16); phase 2: V^T [64][VS]
  __shared__ float Sf[32 * 256];
  __shared__ float mbias[256];
  __shared__ float rmax[32], rsum[32];
  const int t = threadIdx.x;
  const int blk = blockIdx.x;
  const int qt = blk & 7, hh = (blk >> 3) & 15, b = blk >> 7;
  const int q0 = qt * 32;

  mbias[t] = (t == 0) ? 0.0f : ((mask[b * 255 + t - 1] == 1) ? 0.0f : -1e9f);

  {  // stage Q tile (32x64) with XOR chunk swizzle (row&7)
    int row = t >> 3, c = t & 7;
    int gcol = (c ^ (row & 7)) * 8;
    gload16(qkv + (size_t)(b * 256 + q0 + row) * 3072 + hh * 64 + gcol, Qs + t * 8);
  }
#pragma unroll
  for (int s = 0; s < 8; ++s) {  // stage K (256x64), same swizzle
    int row = s * 32 + (t >> 3), c = t & 7;
    int gcol = (c ^ (row & 7)) * 8;
    gload16(qkv + (size_t)(b * 256 + row) * 3072 + 1024 + hh * 64 + gcol,
            KV + s * 2048 + t * 8);
  }
  __syncthreads();

  const int l = t & 63, w = t >> 6;
  const int lr = l & 15, lh = l >> 4;
  {  // QK^T: wave w covers key-cols [w*64, w*64+64)
    const int c0 = w * 64;
    f32x4 acc[2][4] = {};
#pragma unroll
    for (int ks = 0; ks < 2; ++ks) {
      bf16x8 af[2], bfr[4];
#pragma unroll
      for (int m = 0; m < 2; ++m) {
        int row = m * 16 + lr;
        int chunk = (ks * 4 + lh) ^ (row & 7);
        af[m] = ldfrag(Qs + row * 64 + chunk * 8);
      }
#pragma unroll
      for (int n = 0; n < 4; ++n) {
        int row = c0 + n * 16 + lr;
        int chunk = (ks * 4 + lh) ^ (row & 7);
        bfr[n] = ldfrag(KV + row * 64 + chunk * 8);
      }
#pragma unroll
      for (int m = 0; m < 2; ++m)
#pragma unroll
        for (int n = 0; n < 4; ++n) acc[m][n] = mfma16(af[m], bfr[n], acc[m][n]);
    }
#pragma unroll
    for (int m = 0; m < 2; ++m)
#pragma unroll
      for (int n = 0; n < 4; ++n) {
        const int col = c0 + n * 16 + lr;
        const float mb = mbias[col];
#pragma unroll
        for (int j = 0; j < 4; ++j) {
          int row = m * 16 + lh * 4 + j;
          Sf[sfi(row, col)] = acc[m][n][j] * 0.125f + mb;
        }
      }
  }
  __syncthreads();  // Sf ready; K no longer needed

  // issue V loads early (coalesced-ish 64B groups), hide under softmax stats
  ushort8 vreg[4][2];
#pragma unroll
  for (int s = 0; s < 4; ++s) {
    const int j = s * 64 + (t >> 2);
    const u16* vsrc =
        qkv + (size_t)(b * 256 + j) * 3072 + 2048 + hh * 64 + (t & 3) * 16;
    vreg[s][0] = *reinterpret_cast<const ushort8*>(vsrc);
    vreg[s][1] = *reinterpret_cast<const ushort8*>(vsrc + 8);
  }

  {  // row softmax stats: 8 threads per row
    const int row = t >> 3, tg = t & 7;
    float mx = -1e30f;
#pragma unroll 8
    for (int k = 0; k < 32; ++k) mx = fmaxf(mx, Sf[sfi(row, tg * 32 + k)]);
    mx = fmaxf(mx, __shfl_xor(mx, 1));
    mx = fmaxf(mx, __shfl_xor(mx, 2));
    mx = fmaxf(mx, __shfl_xor(mx, 4));
    float sm = 0.f;
#pragma unroll 8
    for (int k = 0; k < 32; ++k) sm += __expf(Sf[sfi(row, tg * 32 + k)] - mx);
    sm += __shfl_xor(sm, 1);
    sm += __shfl_xor(sm, 2);
    sm += __shfl_xor(sm, 4);
    if (tg == 0) {
      rmax[row] = mx;
      rsum[row] = 1.0f / sm;
    }
  }

  // write V^T into KV (overwrites K region)
#pragma unroll
  for (int s = 0; s < 4; ++s) {
    const int j = s * 64 + (t >> 2);
    const int d0 = (t & 3) * 16;
#pragma unroll
    for (int e = 0; e < 8; ++e) {
      KV[(d0 + e) * VS + j] = vreg[s][0][e];
      KV[(d0 + 8 + e) * VS + j] = vreg[s][1][e];
    }
  }
  __syncthreads();  // V^T + softmax stats ready

  // write normalized attention (f32) to d_out
  const size_t obase = ((size_t)b * 16 + hh) * 65536 + (size_t)q0 * 256;
#pragma unroll 4
  for (int i = 0; i < 32; ++i) {
    float p = __expf(Sf[sfi(i, t)] - rmax[i]) * rsum[i];
    att_out[obase + (size_t)i * 256 + t] = p;
  }

  // PV: wave w -> rows [(w&1)*16,+16), cols [(w>>1)*32,+32); P from Sf on the fly
  {
    const int mrow = (w & 1) * 16;
    const int n0c = (w >> 1) * 32;
    const int rr = mrow + lr;
    const float mxl = rmax[rr], rsl = rsum[rr];
    f32x4 acc2[2] = {};
#pragma unroll
    for (int ks = 0; ks < 8; ++ks) {
      const int kbase = ks * 32 + lh * 8;
      const int ch = (kbase >> 3) ^ (rr & 7);
      const float* sp = &Sf[rr * 256 + ch * 8];
      f32x4 s0 = *reinterpret_cast<const f32x4*>(sp);
      f32x4 s1 = *reinterpret_cast<const f32x4*>(sp + 4);
      ushort8 pu;
#pragma unroll
      for (int e = 0; e < 4; ++e) pu[e] = f2b(__expf(s0[e] - mxl) * rsl);
#pragma unroll
      for (int e = 0; e < 4; ++e) pu[4 + e] = f2b(__expf(s1[e] - mxl) * rsl);
      bf16x8 af = __builtin_bit_cast(bf16x8, pu);
#pragma unroll
      for (int n = 0; n < 2; ++n) {
        bf16x8 bfr = ldfrag(KV + (n0c + n * 16 + lr) * VS + kbase);
        acc2[n] = mfma16(af, bfr, acc2[n]);
      }
    }
#pragma unroll
    for (int n = 0; n < 2; ++n)
#pragma unroll
      for (int j = 0; j < 4; ++j) {
        int row = mrow + lh * 4 + j;
        int col = n0c + n * 16 + lr;
        y[(size_t)(b * 256 + q0 + row) * 1024 + hh * 64 + col] = f2b(acc2[n][j]);
      }
  }
}

extern "C" void kernel_launch(void* const* d_in, const int* in_sizes, int n_in,
                              void* d_out, int out_size, void* d_ws, size_t ws_size,
                              hipStream_t stream) {
  (void)in_sizes; (void)n_in; (void)out_size;
  const float* x      = (const float*)d_in[0];
  const int* mask     = (const int*)d_in[1];
  // d_in[2] = is_train (0 in eval; input-drop loop is a no-op)
  const float* sum_emb = (const float*)d_in[3];
  const float* mod_emb = (const float*)d_in[4];
  const float* ln1_w  = (const float*)d_in[5];
  const float* ln1_b  = (const float*)d_in[6];
  const float* w_qkv  = (const float*)d_in[7];
  const float* b_qkv  = (const float*)d_in[8];
  const float* w_proj = (const float*)d_in[9];
  const float* b_proj = (const float*)d_in[10];
  const float* ln2_w  = (const float*)d_in[11];
  const float* ln2_b  = (const float*)d_in[12];
  const float* w_fc   = (const float*)d_in[13];
  const float* b_fc   = (const float*)d_in[14];
  const float* w_out  = (const float*)d_in[15];
  const float* b_out  = (const float*)d_in[16];
  const float* norm_w = (const float*)d_in[17];
  const float* norm_b = (const float*)d_in[18];

  // workspace carve
  char* ws = (char*)d_ws;
  float* h    = (float*)(ws + 0);            // [2048,1024] f32 residual (8 MB)
  u16* a_bf   = (u16*)(ws + 8388608);        // [2048,1024] LN out (4 MB)
  u16* qkv_bf = (u16*)(ws + 12582912);       // [2048,3072] (12.58 MB)
  u16* y_bf   = (u16*)(ws + 25165824);       // [2048,1024] (4 MB)
  u16* g_bf   = (u16*)(ws + 29360128);       // [2048,4096] (16.78 MB)
  u16* wqkvT  = (u16*)(ws + 46137344);       // up to 8x [3072][1024]
  u16* wprojT = (u16*)(ws + 96468992);       // up to 8x [1024][1024]
  u16* wfcT   = (u16*)(ws + 113246208);      // up to 8x [4096][1024]
  u16* woutT  = (u16*)(ws + 180355072);      // up to 8x [1024][4096]
  float* att_f = (float*)d_out + 8192;

  const bool big = ws_size >= 248000000ull;  // all-layer weight staging fits?
  const size_t stq = big ? (size_t)3072 * 1024 : 0;
  const size_t stp = big ? (size_t)1024 * 1024 : 0;
  const size_t stf = big ? (size_t)4096 * 1024 : 0;
  const size_t sto = big ? (size_t)4096 * 1024 : 0;

  embed_k<<<8192, 256, 0, stream>>>(x, sum_emb, mod_emb, h);

  if (big) {  // transpose all layers' weights up-front (4 launches)
    transpose_w<<<dim3(96, 32, 8), 256, 0, stream>>>(w_qkv, wqkvT, 1024, 3072);
    transpose_w<<<dim3(32, 32, 8), 256, 0, stream>>>(w_proj, wprojT, 1024, 1024);
    transpose_w<<<dim3(128, 32, 8), 256, 0, stream>>>(w_fc, wfcT, 1024, 4096);
    transpose_w<<<dim3(32, 128, 8), 256, 0, stream>>>(w_out, woutT, 4096, 1024);
  }

  for (int L = 0; L < 8; ++L) {
    if (!big) {
      transpose_w<<<dim3(96, 32, 1), 256, 0, stream>>>(
          w_qkv + (size_t)L * 1024 * 3072, wqkvT, 1024, 3072);
      transpose_w<<<dim3(32, 32, 1), 256, 0, stream>>>(
          w_proj + (size_t)L * 1024 * 1024, wprojT, 1024, 1024);
      transpose_w<<<dim3(128, 32, 1), 256, 0, stream>>>(
          w_fc + (size_t)L * 1024 * 4096, wfcT, 1024, 4096);
      transpose_w<<<dim3(32, 128, 1), 256, 0, stream>>>(
          w_out + (size_t)L * 4096 * 1024, woutT, 4096, 1024);
    }
    ln_bf16<<<2048, 256, 0, stream>>>(h, ln1_w + L * 1024, ln1_b + L * 1024, a_bf);
    gemm_bt<0, 1><<<dim3(24, 16, 1), 256, 0, stream>>>(
        a_bf, wqkvT + L * stq, b_qkv + L * 3072, nullptr, qkv_bf, 2048, 3072, 1024);
    attn_fused<<<1024, 256, 0, stream>>>(qkv_bf, mask,
                                         att_f + (size_t)L * 8388608, y_bf);
    gemm_bt<1, 2><<<dim3(8, 16, 2), 256, 0, stream>>>(
        y_bf, wprojT + L * stp, b_proj + L * 1024, h, nullptr, 2048, 1024, 1024);
    ln_bf16<<<2048, 256, 0, stream>>>(h, ln2_w + L * 1024, ln2_b + L * 1024, a_bf);
    gemm_bt<2, 1><<<dim3(32, 16, 1), 256, 0, stream>>>(
        a_bf, wfcT + L * stf, b_fc + L * 4096, nullptr, g_bf, 2048, 4096, 1024);
    gemm_bt<1, 4><<<dim3(8, 16, 4), 256, 0, stream>>>(
        g_bf, woutT + L * sto, b_out + L * 1024, h, nullptr, 2048, 1024, 4096);
  }

  final_ln<<<8, 256, 0, stream>>>(h, norm_w, norm_b, (float*)d_out);
}

// Round 6
// 2099.710 us; speedup vs baseline: 1.1966x; 1.0047x over previous
//
#include <hip/hip_runtime.h>

// MaskedAtten: 8-layer transformer encoder fwd on MI355X (gfx950).
// B=8, T=255 -> L=256, D=1024, H=16, DH=64, NL=8, DFF=4096.
// Outputs: h[:,0] (8x1024 f32) then all_att (8,8,16,256,256 f32), concat flat.

using u16 = unsigned short;
typedef __attribute__((ext_vector_type(8))) __bf16 bf16x8;
typedef __attribute__((ext_vector_type(4))) float f32x4;
typedef __attribute__((ext_vector_type(8))) unsigned short ushort8;

__device__ __forceinline__ u16 f2b(float f) {
  unsigned u = __builtin_bit_cast(unsigned, f);
  return (u16)((u + 0x7FFFu + ((u >> 16) & 1u)) >> 16);  // RNE f32->bf16
}

__device__ __forceinline__ bf16x8 ldfrag(const u16* p) {
  return *reinterpret_cast<const bf16x8*>(p);
}

__device__ __forceinline__ f32x4 mfma16(bf16x8 a, bf16x8 b, f32x4 c) {
  return __builtin_amdgcn_mfma_f32_16x16x32_bf16(a, b, c, 0, 0, 0);
}

// async global->LDS, 16B per lane. LDS dest is wave-uniform base + lane*16.
__device__ __forceinline__ void gload16(const void* g, void* l) {
  __builtin_amdgcn_global_load_lds(
      (const __attribute__((address_space(1))) unsigned int*)g,
      (__attribute__((address_space(3))) unsigned int*)l, 16, 0, 0);
}

// ---------------- embed: h[b,l,d] = (l==0 ? sum_emb : x[b,l-1]) + mod_emb[l]
__global__ __launch_bounds__(256) void embed_k(
    const float* __restrict__ x, const float* __restrict__ sum_emb,
    const float* __restrict__ mod_emb, float* __restrict__ h) {
  int idx = blockIdx.x * 256 + threadIdx.x;  // 8*256*1024 total
  int d = idx & 1023;
  int l = (idx >> 10) & 255;
  int b = idx >> 18;
  float v = (l == 0) ? sum_emb[d] : x[(size_t)(b * 255 + l - 1) * 1024 + d];
  h[idx] = v + mod_emb[l * 1024 + d];
}

// ---------------- weight transpose + cast: in f32 [R][C] -> out bf16 [C][R]
// blockIdx.z = layer (in/out advance by R*C elements per layer)
__global__ __launch_bounds__(256) void transpose_w(
    const float* __restrict__ in, u16* __restrict__ out, int R, int C) {
  __shared__ float tile[32][33];
  in += (size_t)blockIdx.z * R * C;
  out += (size_t)blockIdx.z * R * C;
  const int t = threadIdx.x;
  const int r0 = blockIdx.y * 32, c0 = blockIdx.x * 32;
  const int tr = t >> 5, tc = t & 31;
#pragma unroll
  for (int i = 0; i < 4; ++i)
    tile[tr + i * 8][tc] = in[(size_t)(r0 + tr + i * 8) * C + c0 + tc];
  __syncthreads();
#pragma unroll
  for (int i = 0; i < 4; ++i) {
    int cc = tr + i * 8, rr = tc;
    out[(size_t)(c0 + cc) * R + r0 + rr] = f2b(tile[rr][cc]);
  }
}

// ---------------- LayerNorm row (1024) -> bf16 out, affine w,b
__global__ __launch_bounds__(256) void ln_bf16(
    const float* __restrict__ x, const float* __restrict__ w,
    const float* __restrict__ bb, u16* __restrict__ out) {
  const int r = blockIdx.x, t = threadIdx.x;
  const float* xr = x + (size_t)r * 1024;
  float v[4], s1 = 0.f, s2 = 0.f;
#pragma unroll
  for (int i = 0; i < 4; ++i) {
    v[i] = xr[t + i * 256];
    s1 += v[i];
    s2 += v[i] * v[i];
  }
#pragma unroll
  for (int o = 32; o > 0; o >>= 1) {
    s1 += __shfl_down(s1, o);
    s2 += __shfl_down(s2, o);
  }
  __shared__ float red[8];
  const int wv = t >> 6, l = t & 63;
  if (l == 0) { red[wv] = s1; red[4 + wv] = s2; }
  __syncthreads();
  s1 = red[0] + red[1] + red[2] + red[3];
  s2 = red[4] + red[5] + red[6] + red[7];
  float mean = s1 * (1.0f / 1024.0f);
  float var = s2 * (1.0f / 1024.0f) - mean * mean;
  float rstd = rsqrtf(var + 1e-5f);
#pragma unroll
  for (int i = 0; i < 4; ++i) {
    int c = t + i * 256;
    out[(size_t)r * 1024 + c] = f2b((v[i] - mean) * rstd * w[c] + bb[c]);
  }
}

// ---------------- final LN on the 8 summary rows -> f32 d_out[0:8192]
__global__ __launch_bounds__(256) void final_ln(
    const float* __restrict__ h, const float* __restrict__ w,
    const float* __restrict__ bb, float* __restrict__ out) {
  const int r = blockIdx.x, t = threadIdx.x;
  const float* xr = h + (size_t)r * 262144;  // row (b,0)
  float v[4], s1 = 0.f, s2 = 0.f;
#pragma unroll
  for (int i = 0; i < 4; ++i) {
    v[i] = xr[t + i * 256];
    s1 += v[i];
    s2 += v[i] * v[i];
  }
#pragma unroll
  for (int o = 32; o > 0; o >>= 1) {
    s1 += __shfl_down(s1, o);
    s2 += __shfl_down(s2, o);
  }
  __shared__ float red[8];
  const int wv = t >> 6, l = t & 63;
  if (l == 0) { red[wv] = s1; red[4 + wv] = s2; }
  __syncthreads();
  s1 = red[0] + red[1] + red[2] + red[3];
  s2 = red[4] + red[5] + red[6] + red[7];
  float mean = s1 * (1.0f / 1024.0f);
  float var = s2 * (1.0f / 1024.0f) - mean * mean;
  float rstd = rsqrtf(var + 1e-5f);
#pragma unroll
  for (int i = 0; i < 4; ++i) {
    int c = t + i * 256;
    out[r * 1024 + c] = (v[i] - mean) * rstd * w[c] + bb[c];
  }
}

// ---------------- GEMM (2-phase prefetch): C[M,N] = A[M,K] @ BT[N,K]^T + bias
// BM=128, BN=256, BK=64, 8 waves (512 thr), LDS double-buffered (96 KB).
// T3-minimum schedule: stage(kt+1) issued BEFORE ds_read/MFMA of kt; one
// __syncthreads per K-tile (compiler drains vmcnt+lgkmcnt before s_barrier).
// XOR chunk swizzle (chunk ^= row&7) on stage-source AND ds_read (T2, rule #21).
// EPI 0: bf16 out ; EPI 1: atomicAdd into Hres f32 (+bias at kz==0) ; EPI 2: gelu->bf16
template <int EPI, int SPLIT>
__global__ __launch_bounds__(512) void gemm2p(
    const u16* __restrict__ A, const u16* __restrict__ BT,
    const float* __restrict__ bias, float* __restrict__ Hres,
    u16* __restrict__ Obf, int M, int N, int K) {
  __shared__ u16 As[2][128 * 64];
  __shared__ u16 Bs[2][256 * 64];
  const int t = threadIdx.x;
  // T1: bijective XCD swizzle (all grids here have gx*gy % 8 == 0)
  const int gx = gridDim.x, nwg = gx * gridDim.y;
  int id = blockIdx.y * gx + blockIdx.x;
  id = (id & 7) * (nwg >> 3) + (id >> 3);
  const int m0 = (id / gx) * 128, n0 = (id % gx) * 256;

  const int Kl = K / SPLIT;
  const int kz = (SPLIT > 1) ? blockIdx.z : 0;
  A += (size_t)kz * Kl;
  BT += (size_t)kz * Kl;

  const int l = t & 63, w = t >> 6;
  const int wm = w >> 2, wn = w & 3;          // 2 x 4 wave grid
  const int lr = l & 15, lh = l >> 4;

  // staging geometry: thread t -> row (t>>3), chunk (t&7) of 8 bf16 (16B)
  const int sr = t >> 3, sc = t & 7;
  const int scA = (sc ^ (sr & 7)) * 8;        // pre-swizzled source chunk

  f32x4 acc[4][4] = {};
  const int nk = Kl / 64;
  int cur = 0;

#define STAGE_TILE(bb, kt)                                                     \
  {                                                                            \
    const size_t kof = (size_t)(kt)*64 + scA;                                  \
    gload16(A + (size_t)(m0 + sr) * K + kof, &As[bb][t * 8]);                  \
    gload16(A + (size_t)(m0 + sr + 64) * K + kof, &As[bb][4096 + t * 8]);      \
    gload16(BT + (size_t)(n0 + sr) * K + kof, &Bs[bb][t * 8]);                 \
    gload16(BT + (size_t)(n0 + sr + 64) * K + kof, &Bs[bb][4096 + t * 8]);     \
    gload16(BT + (size_t)(n0 + sr + 128) * K + kof, &Bs[bb][8192 + t * 8]);    \
    gload16(BT + (size_t)(n0 + sr + 192) * K + kof, &Bs[bb][12288 + t * 8]);   \
  }

  STAGE_TILE(0, 0);
  __syncthreads();  // drains vmcnt before barrier -> tile 0 resident

  for (int kt = 0; kt < nk; ++kt) {
    if (kt + 1 < nk) STAGE_TILE(cur ^ 1, kt + 1);
    bf16x8 af[4][2], bfr[4][2];
#pragma unroll
    for (int ks = 0; ks < 2; ++ks) {
#pragma unroll
      for (int m = 0; m < 4; ++m) {
        const int row = wm * 64 + m * 16 + lr;
        af[m][ks] = ldfrag(&As[cur][row * 64 + (((ks * 4 + lh) ^ (row & 7)) << 3)]);
      }
#pragma unroll
      for (int n = 0; n < 4; ++n) {
        const int row = wn * 64 + n * 16 + lr;
        bfr[n][ks] = ldfrag(&Bs[cur][row * 64 + (((ks * 4 + lh) ^ (row & 7)) << 3)]);
      }
    }
#pragma unroll
    for (int ks = 0; ks < 2; ++ks)
#pragma unroll
      for (int m = 0; m < 4; ++m)
#pragma unroll
        for (int n = 0; n < 4; ++n) acc[m][n] = mfma16(af[m][ks], bfr[n][ks], acc[m][n]);
    __syncthreads();  // all waves done with cur; next tile (cur^1) drained
    cur ^= 1;
  }
#undef STAGE_TILE

#pragma unroll
  for (int m = 0; m < 4; ++m) {
#pragma unroll
    for (int n = 0; n < 4; ++n) {
      const int col = n0 + wn * 64 + n * 16 + lr;
      const float bc = (SPLIT == 1 || kz == 0) ? bias[col] : 0.0f;
#pragma unroll
      for (int j = 0; j < 4; ++j) {
        const int row = m0 + wm * 64 + m * 16 + lh * 4 + j;
        float v = acc[m][n][j] + bc;
        if (EPI == 0) {
          Obf[(size_t)row * N + col] = f2b(v);
        } else if (EPI == 1) {
          size_t idx = (size_t)row * N + col;
          if (SPLIT == 1) Hres[idx] = Hres[idx] + v;
          else atomicAdd(Hres + idx, v);
        } else {
          float g = 0.5f * v *
                    (1.0f + tanhf(0.7978845608028654f * (v + 0.044715f * v * v * v)));
          Obf[(size_t)row * N + col] = f2b(g);
        }
      }
    }
  }
}

// ---------------- fused attention per (b, head, 32-row q-tile):
// QK^T -> softmax -> write att f32 (d_out) -> PV -> write y bf16.
#define VS 264  // padded row stride for transposed V (conflict-free b128)
__device__ __forceinline__ int sfi(int row, int col) {
  return row * 256 + ((col & 7) | (((col >> 3) ^ (row & 7)) << 3));
}

__global__ __launch_bounds__(256) void attn_fused(
    const u16* __restrict__ qkv, const int* __restrict__ mask,
    float* __restrict__ att_out, u16* __restrict__ y) {
  __shared__ u16 Qs[32 * 64];
  __shared__ u16 KV[64 * VS];  // phase 1: K (256x64 = 16384 u16); phase 2: V^T [64][VS]
  __shared__ float Sf[32 * 256];
  __shared__ float mbias[256];
  __shared__ float rmax[32], rsum[32];
  const int t = threadIdx.x;
  const int blk = blockIdx.x;
  const int qt = blk & 7, hh = (blk >> 3) & 15, b = blk >> 7;
  const int q0 = qt * 32;

  mbias[t] = (t == 0) ? 0.0f : ((mask[b * 255 + t - 1] == 1) ? 0.0f : -1e9f);

  {  // stage Q tile (32x64) with XOR chunk swizzle (row&7)
    int row = t >> 3, c = t & 7;
    int gcol = (c ^ (row & 7)) * 8;
    gload16(qkv + (size_t)(b * 256 + q0 + row) * 3072 + hh * 64 + gcol, Qs + t * 8);
  }
#pragma unroll
  for (int s = 0; s < 8; ++s) {  // stage K (256x64), same swizzle
    int row = s * 32 + (t >> 3), c = t & 7;
    int gcol = (c ^ (row & 7)) * 8;
    gload16(qkv + (size_t)(b * 256 + row) * 3072 + 1024 + hh * 64 + gcol,
            KV + s * 2048 + t * 8);
  }
  __syncthreads();

  const int l = t & 63, w = t >> 6;
  const int lr = l & 15, lh = l >> 4;
  {  // QK^T: wave w covers key-cols [w*64, w*64+64)
    const int c0 = w * 64;
    f32x4 acc[2][4] = {};
#pragma unroll
    for (int ks = 0; ks < 2; ++ks) {
      bf16x8 af[2], bfr[4];
#pragma unroll
      for (int m = 0; m < 2; ++m) {
        int row = m * 16 + lr;
        int chunk = (ks * 4 + lh) ^ (row & 7);
        af[m] = ldfrag(Qs + row * 64 + chunk * 8);
      }
#pragma unroll
      for (int n = 0; n < 4; ++n) {
        int row = c0 + n * 16 + lr;
        int chunk = (ks * 4 + lh) ^ (row & 7);
        bfr[n] = ldfrag(KV + row * 64 + chunk * 8);
      }
#pragma unroll
      for (int m = 0; m < 2; ++m)
#pragma unroll
        for (int n = 0; n < 4; ++n) acc[m][n] = mfma16(af[m], bfr[n], acc[m][n]);
    }
#pragma unroll
    for (int m = 0; m < 2; ++m)
#pragma unroll
      for (int n = 0; n < 4; ++n) {
        const int col = c0 + n * 16 + lr;
        const float mb = mbias[col];
#pragma unroll
        for (int j = 0; j < 4; ++j) {
          int row = m * 16 + lh * 4 + j;
          Sf[sfi(row, col)] = acc[m][n][j] * 0.125f + mb;
        }
      }
  }
  __syncthreads();  // Sf ready; K no longer needed

  // issue V loads early (coalesced-ish 64B groups), hide under softmax stats
  ushort8 vreg[4][2];
#pragma unroll
  for (int s = 0; s < 4; ++s) {
    const int j = s * 64 + (t >> 2);
    const u16* vsrc =
        qkv + (size_t)(b * 256 + j) * 3072 + 2048 + hh * 64 + (t & 3) * 16;
    vreg[s][0] = *reinterpret_cast<const ushort8*>(vsrc);
    vreg[s][1] = *reinterpret_cast<const ushort8*>(vsrc + 8);
  }

  {  // row softmax stats: 8 threads per row
    const int row = t >> 3, tg = t & 7;
    float mx = -1e30f;
#pragma unroll 8
    for (int k = 0; k < 32; ++k) mx = fmaxf(mx, Sf[sfi(row, tg * 32 + k)]);
    mx = fmaxf(mx, __shfl_xor(mx, 1));
    mx = fmaxf(mx, __shfl_xor(mx, 2));
    mx = fmaxf(mx, __shfl_xor(mx, 4));
    float sm = 0.f;
#pragma unroll 8
    for (int k = 0; k < 32; ++k) sm += __expf(Sf[sfi(row, tg * 32 + k)] - mx);
    sm += __shfl_xor(sm, 1);
    sm += __shfl_xor(sm, 2);
    sm += __shfl_xor(sm, 4);
    if (tg == 0) {
      rmax[row] = mx;
      rsum[row] = 1.0f / sm;
    }
  }

  // write V^T into KV (overwrites K region)
#pragma unroll
  for (int s = 0; s < 4; ++s) {
    const int j = s * 64 + (t >> 2);
    const int d0 = (t & 3) * 16;
#pragma unroll
    for (int e = 0; e < 8; ++e) {
      KV[(d0 + e) * VS + j] = vreg[s][0][e];
      KV[(d0 + 8 + e) * VS + j] = vreg[s][1][e];
    }
  }
  __syncthreads();  // V^T + softmax stats ready

  // write normalized attention (f32) to d_out
  const size_t obase = ((size_t)b * 16 + hh) * 65536 + (size_t)q0 * 256;
#pragma unroll 4
  for (int i = 0; i < 32; ++i) {
    float p = __expf(Sf[sfi(i, t)] - rmax[i]) * rsum[i];
    att_out[obase + (size_t)i * 256 + t] = p;
  }

  // PV: wave w -> rows [(w&1)*16,+16), cols [(w>>1)*32,+32); P from Sf on the fly
  {
    const int mrow = (w & 1) * 16;
    const int n0c = (w >> 1) * 32;
    const int rr = mrow + lr;
    const float mxl = rmax[rr], rsl = rsum[rr];
    f32x4 acc2[2] = {};
#pragma unroll
    for (int ks = 0; ks < 8; ++ks) {
      const int kbase = ks * 32 + lh * 8;
      const int ch = (kbase >> 3) ^ (rr & 7);
      const float* sp = &Sf[rr * 256 + ch * 8];
      f32x4 s0 = *reinterpret_cast<const f32x4*>(sp);
      f32x4 s1 = *reinterpret_cast<const f32x4*>(sp + 4);
      ushort8 pu;
#pragma unroll
      for (int e = 0; e < 4; ++e) pu[e] = f2b(__expf(s0[e] - mxl) * rsl);
#pragma unroll
      for (int e = 0; e < 4; ++e) pu[4 + e] = f2b(__expf(s1[e] - mxl) * rsl);
      bf16x8 af = __builtin_bit_cast(bf16x8, pu);
#pragma unroll
      for (int n = 0; n < 2; ++n) {
        bf16x8 bfr = ldfrag(KV + (n0c + n * 16 + lr) * VS + kbase);
        acc2[n] = mfma16(af, bfr, acc2[n]);
      }
    }
#pragma unroll
    for (int n = 0; n < 2; ++n)
#pragma unroll
      for (int j = 0; j < 4; ++j) {
        int row = mrow + lh * 4 + j;
        int col = n0c + n * 16 + lr;
        y[(size_t)(b * 256 + q0 + row) * 1024 + hh * 64 + col] = f2b(acc2[n][j]);
      }
  }
}

extern "C" void kernel_launch(void* const* d_in, const int* in_sizes, int n_in,
                              void* d_out, int out_size, void* d_ws, size_t ws_size,
                              hipStream_t stream) {
  (void)in_sizes; (void)n_in; (void)out_size;
  const float* x      = (const float*)d_in[0];
  const int* mask     = (const int*)d_in[1];
  // d_in[2] = is_train (0 in eval; input-drop loop is a no-op)
  const float* sum_emb = (const float*)d_in[3];
  const float* mod_emb = (const float*)d_in[4];
  const float* ln1_w  = (const float*)d_in[5];
  const float* ln1_b  = (const float*)d_in[6];
  const float* w_qkv  = (const float*)d_in[7];
  const float* b_qkv  = (const float*)d_in[8];
  const float* w_proj = (const float*)d_in[9];
  const float* b_proj = (const float*)d_in[10];
  const float* ln2_w  = (const float*)d_in[11];
  const float* ln2_b  = (const float*)d_in[12];
  const float* w_fc   = (const float*)d_in[13];
  const float* b_fc   = (const float*)d_in[14];
  const float* w_out  = (const float*)d_in[15];
  const float* b_out  = (const float*)d_in[16];
  const float* norm_w = (const float*)d_in[17];
  const float* norm_b = (const float*)d_in[18];

  // workspace carve
  char* ws = (char*)d_ws;
  float* h    = (float*)(ws + 0);            // [2048,1024] f32 residual (8 MB)
  u16* a_bf   = (u16*)(ws + 8388608);        // [2048,1024] LN out (4 MB)
  u16* qkv_bf = (u16*)(ws + 12582912);       // [2048,3072] (12.58 MB)
  u16* y_bf   = (u16*)(ws + 25165824);       // [2048,1024] (4 MB)
  u16* g_bf   = (u16*)(ws + 29360128);       // [2048,4096] (16.78 MB)
  u16* wqkvT  = (u16*)(ws + 46137344);       // up to 8x [3072][1024]
  u16* wprojT = (u16*)(ws + 96468992);       // up to 8x [1024][1024]
  u16* wfcT   = (u16*)(ws + 113246208);      // up to 8x [4096][1024]
  u16* woutT  = (u16*)(ws + 180355072);      // up to 8x [1024][4096]
  float* att_f = (float*)d_out + 8192;

  const bool big = ws_size >= 248000000ull;  // all-layer weight staging fits?
  const size_t stq = big ? (size_t)3072 * 1024 : 0;
  const size_t stp = big ? (size_t)1024 * 1024 : 0;
  const size_t stf = big ? (size_t)4096 * 1024 : 0;
  const size_t sto = big ? (size_t)4096 * 1024 : 0;

  embed_k<<<8192, 256, 0, stream>>>(x, sum_emb, mod_emb, h);

  if (big) {  // transpose all layers' weights up-front (4 launches)
    transpose_w<<<dim3(96, 32, 8), 256, 0, stream>>>(w_qkv, wqkvT, 1024, 3072);
    transpose_w<<<dim3(32, 32, 8), 256, 0, stream>>>(w_proj, wprojT, 1024, 1024);
    transpose_w<<<dim3(128, 32, 8), 256, 0, stream>>>(w_fc, wfcT, 1024, 4096);
    transpose_w<<<dim3(32, 128, 8), 256, 0, stream>>>(w_out, woutT, 4096, 1024);
  }

  for (int L = 0; L < 8; ++L) {
    if (!big) {
      transpose_w<<<dim3(96, 32, 1), 256, 0, stream>>>(
          w_qkv + (size_t)L * 1024 * 3072, wqkvT, 1024, 3072);
      transpose_w<<<dim3(32, 32, 1), 256, 0, stream>>>(
          w_proj + (size_t)L * 1024 * 1024, wprojT, 1024, 1024);
      transpose_w<<<dim3(128, 32, 1), 256, 0, stream>>>(
          w_fc + (size_t)L * 1024 * 4096, wfcT, 1024, 4096);
      transpose_w<<<dim3(32, 128, 1), 256, 0, stream>>>(
          w_out + (size_t)L * 4096 * 1024, woutT, 4096, 1024);
    }
    ln_bf16<<<2048, 256, 0, stream>>>(h, ln1_w + L * 1024, ln1_b + L * 1024, a_bf);
    gemm2p<0, 1><<<dim3(12, 16, 1), 512, 0, stream>>>(
        a_bf, wqkvT + L * stq, b_qkv + L * 3072, nullptr, qkv_bf, 2048, 3072, 1024);
    attn_fused<<<1024, 256, 0, stream>>>(qkv_bf, mask,
                                         att_f + (size_t)L * 8388608, y_bf);
    gemm2p<1, 4><<<dim3(4, 16, 4), 512, 0, stream>>>(
        y_bf, wprojT + L * stp, b_proj + L * 1024, h, nullptr, 2048, 1024, 1024);
    ln_bf16<<<2048, 256, 0, stream>>>(h, ln2_w + L * 1024, ln2_b + L * 1024, a_bf);
    gemm2p<2, 1><<<dim3(16, 16, 1), 512, 0, stream>>>(
        a_bf, wfcT + L * stf, b_fc + L * 4096, nullptr, g_bf, 2048, 4096, 1024);
    gemm2p<1, 4><<<dim3(4, 16, 4), 512, 0, stream>>>(
        g_bf, woutT + L * sto, b_out + L * 1024, h, nullptr, 2048, 1024, 4096);
  }

  final_ln<<<8, 256, 0, stream>>>(h, norm_w, norm_b, (float*)d_out);
}